// Round 1
// baseline (1047.618 us; speedup 1.0000x reference)
//
#include <hip/hip_runtime.h>
#include <math.h>

#define N_NODES 50000
#define N_EDGES 800000
#define HEADS 4
#define HID 64
#define FDIM 256      // HEADS*HID == F_IN == 256 for both layers
#define NROWS 16      // rows per GEMM block

// ---------------------------------------------------------------- CSR build

__global__ __launch_bounds__(256) void hist_kernel(const int* __restrict__ dst,
                                                   int* __restrict__ counts, int E) {
    int i = blockIdx.x * blockDim.x + threadIdx.x;
    if (i < E) atomicAdd(&counts[dst[i]], 1);
}

__global__ __launch_bounds__(1024) void scan_kernel(const int* __restrict__ counts,
                                                    int* __restrict__ offs, int n) {
    __shared__ int partial[1024];
    int t = threadIdx.x;
    int chunk = (n + 1023) / 1024;
    int lo = t * chunk;
    int hi = lo + chunk; if (hi > n) hi = n;
    int s = 0;
    for (int i = lo; i < hi; i++) s += counts[i];
    partial[t] = s;
    __syncthreads();
    // Hillis-Steele inclusive scan over per-thread sums
    for (int off = 1; off < 1024; off <<= 1) {
        int v = 0;
        if (t >= off) v = partial[t - off];
        __syncthreads();
        if (t >= off) partial[t] += v;
        __syncthreads();
    }
    int run = (t > 0) ? partial[t - 1] : 0;
    for (int i = lo; i < hi; i++) { offs[i] = run; run += counts[i]; }
    if (t == 1023) offs[n] = partial[1023];
}

__global__ __launch_bounds__(256) void scatter_kernel(const int* __restrict__ src,
                                                      const int* __restrict__ dst,
                                                      const int* __restrict__ offs,
                                                      int* __restrict__ cursor,
                                                      int* __restrict__ csr_src, int E) {
    int i = blockIdx.x * blockDim.x + threadIdx.x;
    if (i < E) {
        int d = dst[i];
        int p = offs[d] + atomicAdd(&cursor[d], 1);
        csr_src[p] = src[i];
    }
}

// ------------------------------------------------- GEMM + el/er (per layer)
// feat = H @ W   (H: [N,256], W: [256,256] row-major)
// el[n,h] = sum_d feat[n,h*64+d] * a_l[h*64+d]   (same for er)
// Block: 256 threads, 16 rows x 256 cols. Wave w handles rows w*4..w*4+3;
// lane's cols are lane*4..lane*4+3  (head = lane/16).
__global__ __launch_bounds__(256) void gemm_el_er(const float* __restrict__ H,
                                                  const float* __restrict__ W,
                                                  const float* __restrict__ al,
                                                  const float* __restrict__ ar,
                                                  float* __restrict__ feat,
                                                  float* __restrict__ el,
                                                  float* __restrict__ er) {
    __shared__ float hs[NROWS][FDIM];
    const int t = threadIdx.x;
    const int r0 = blockIdx.x * NROWS;
    for (int r = 0; r < NROWS; r++) hs[r][t] = H[(size_t)(r0 + r) * FDIM + t];
    __syncthreads();

    const int wave = t >> 6;
    const int lane = t & 63;
    const int c0 = lane * 4;
    const int rbase = wave * 4;

    float acc[4][4] = {};
    for (int k = 0; k < FDIM; k += 4) {
        float4 w0 = *(const float4*)&W[(k + 0) * FDIM + c0];
        float4 w1 = *(const float4*)&W[(k + 1) * FDIM + c0];
        float4 w2 = *(const float4*)&W[(k + 2) * FDIM + c0];
        float4 w3 = *(const float4*)&W[(k + 3) * FDIM + c0];
#pragma unroll
        for (int r = 0; r < 4; r++) {
            float4 h4 = *(const float4*)&hs[rbase + r][k];
            acc[r][0] += h4.x * w0.x + h4.y * w1.x + h4.z * w2.x + h4.w * w3.x;
            acc[r][1] += h4.x * w0.y + h4.y * w1.y + h4.z * w2.y + h4.w * w3.y;
            acc[r][2] += h4.x * w0.z + h4.y * w1.z + h4.z * w2.z + h4.w * w3.z;
            acc[r][3] += h4.x * w0.w + h4.y * w1.w + h4.z * w2.w + h4.w * w3.w;
        }
    }

    const float4 alv = *(const float4*)&al[c0];
    const float4 arv = *(const float4*)&ar[c0];
    const int head = lane >> 4;

#pragma unroll
    for (int r = 0; r < 4; r++) {
        int n = r0 + rbase + r;
        float4 v = make_float4(acc[r][0], acc[r][1], acc[r][2], acc[r][3]);
        *(float4*)&feat[(size_t)n * FDIM + c0] = v;
        float pl = acc[r][0] * alv.x + acc[r][1] * alv.y + acc[r][2] * alv.z + acc[r][3] * alv.w;
        float pr = acc[r][0] * arv.x + acc[r][1] * arv.y + acc[r][2] * arv.z + acc[r][3] * arv.w;
        for (int off = 8; off; off >>= 1) {
            pl += __shfl_down(pl, off, 16);
            pr += __shfl_down(pr, off, 16);
        }
        if ((lane & 15) == 0) {
            el[n * HEADS + head] = pl;
            er[n * HEADS + head] = pr;
        }
    }
}

// ----------------------------------------------- per-dst softmax + aggregate
// One block per dst node. Wave = head, lane = feature dim d.
// head_major=0: out[n*256 + h*64 + d]   (layer-1 hidden, flatten(1) layout)
// head_major=1: out[h*N*64 + n*64 + d]  (final tuple-of-heads layout)
__global__ __launch_bounds__(256) void aggregate_kernel(const float* __restrict__ feat,
                                                        const float* __restrict__ el,
                                                        const float* __restrict__ er,
                                                        const float* __restrict__ bias,
                                                        const int* __restrict__ offs,
                                                        const int* __restrict__ csr_src,
                                                        float* __restrict__ out,
                                                        int head_major) {
    const int n = blockIdx.x;
    const int h = threadIdx.x >> 6;
    const int d = threadIdx.x & 63;
    const int beg = offs[n];
    const int end = offs[n + 1];
    const float ern = er[n * HEADS + h];

    float m = -1e30f;
    for (int i = beg; i < end; i++) {
        int s = csr_src[i];
        float e = el[s * HEADS + h] + ern;
        e = (e > 0.f) ? e : 0.2f * e;
        m = fmaxf(m, e);
    }

    float ssum = 0.f, acc = 0.f;
    for (int i = beg; i < end; i++) {
        int s = csr_src[i];
        float e = el[s * HEADS + h] + ern;
        e = (e > 0.f) ? e : 0.2f * e;
        float ex = __expf(e - m);
        ssum += ex;
        acc += ex * feat[(size_t)s * FDIM + h * HID + d];
    }

    float r = acc / fmaxf(ssum, 1e-9f) + bias[h * HID + d];
    r = (r > 0.f) ? r : expm1f(r);
    size_t oidx = head_major ? ((size_t)h * N_NODES * HID + (size_t)n * HID + d)
                             : ((size_t)n * FDIM + h * HID + d);
    out[oidx] = r;
}

// ---------------------------------------------------------------- launch

extern "C" void kernel_launch(void* const* d_in, const int* in_sizes, int n_in,
                              void* d_out, int out_size, void* d_ws, size_t ws_size,
                              hipStream_t stream) {
    const float* x   = (const float*)d_in[0];
    const int*   src = (const int*)d_in[1];
    const int*   dst = (const int*)d_in[2];
    const float* W0  = (const float*)d_in[3];
    const float* al0 = (const float*)d_in[4];
    const float* ar0 = (const float*)d_in[5];
    const float* b0  = (const float*)d_in[6];
    const float* W1  = (const float*)d_in[7];
    const float* al1 = (const float*)d_in[8];
    const float* ar1 = (const float*)d_in[9];
    const float* b1  = (const float*)d_in[10];
    float* out = (float*)d_out;

    // workspace layout (fp32 words)
    float* feat = (float*)d_ws;                        // N*256
    float* el   = feat + (size_t)N_NODES * FDIM;       // N*4
    float* er   = el + N_NODES * HEADS;                // N*4
    int* counts  = (int*)(er + N_NODES * HEADS);       // N
    int* cursor  = counts + N_NODES;                   // N
    int* offs    = cursor + N_NODES;                   // N+1
    int* csr_src = offs + (N_NODES + 1);               // E

    // ---- CSR build (graph identical for both layers)
    hipMemsetAsync(counts, 0, 2 * N_NODES * sizeof(int), stream);  // counts + cursor
    hist_kernel<<<(N_EDGES + 255) / 256, 256, 0, stream>>>(dst, counts, N_EDGES);
    scan_kernel<<<1, 1024, 0, stream>>>(counts, offs, N_NODES);
    scatter_kernel<<<(N_EDGES + 255) / 256, 256, 0, stream>>>(src, dst, offs, cursor, csr_src, N_EDGES);

    // ---- layer 1 (hidden h1 stored in d_out as [N,256])
    gemm_el_er<<<N_NODES / NROWS, 256, 0, stream>>>(x, W0, al0, ar0, feat, el, er);
    aggregate_kernel<<<N_NODES, 256, 0, stream>>>(feat, el, er, b0, offs, csr_src, out, 0);

    // ---- layer 2 (reads h1 from d_out, final write head-major over d_out)
    gemm_el_er<<<N_NODES / NROWS, 256, 0, stream>>>(out, W1, al1, ar1, feat, el, er);
    aggregate_kernel<<<N_NODES, 256, 0, stream>>>(feat, el, er, b1, offs, csr_src, out, 1);
}

// Round 2
// 814.091 us; speedup vs baseline: 1.2869x; 1.2869x over previous
//
#include <hip/hip_runtime.h>
#include <math.h>

#define N_NODES 50000
#define N_EDGES 800000
#define HEADS 4
#define HID 64
#define FDIM 256      // HEADS*HID == F_IN == 256 for both layers
#define NROWS 16      // rows per GEMM block

// ---------------------------------------------------------------- CSR build

__global__ __launch_bounds__(256) void hist_kernel(const int* __restrict__ dst,
                                                   int* __restrict__ counts, int E) {
    int i = blockIdx.x * blockDim.x + threadIdx.x;
    if (i < E) atomicAdd(&counts[dst[i]], 1);
}

__global__ __launch_bounds__(1024) void scan_kernel(const int* __restrict__ counts,
                                                    int* __restrict__ offs, int n) {
    __shared__ int partial[1024];
    int t = threadIdx.x;
    int chunk = (n + 1023) / 1024;
    int lo = t * chunk;
    int hi = lo + chunk; if (hi > n) hi = n;
    int s = 0;
    for (int i = lo; i < hi; i++) s += counts[i];
    partial[t] = s;
    __syncthreads();
    for (int off = 1; off < 1024; off <<= 1) {
        int v = 0;
        if (t >= off) v = partial[t - off];
        __syncthreads();
        if (t >= off) partial[t] += v;
        __syncthreads();
    }
    int run = (t > 0) ? partial[t - 1] : 0;
    for (int i = lo; i < hi; i++) { offs[i] = run; run += counts[i]; }
    if (t == 1023) offs[n] = partial[1023];
}

__global__ __launch_bounds__(256) void scatter_kernel(const int* __restrict__ src,
                                                      const int* __restrict__ dst,
                                                      const int* __restrict__ offs,
                                                      int* __restrict__ cursor,
                                                      int* __restrict__ csr_src, int E) {
    int i = blockIdx.x * blockDim.x + threadIdx.x;
    if (i < E) {
        int d = dst[i];
        int p = offs[d] + atomicAdd(&cursor[d], 1);
        csr_src[p] = src[i];
    }
}

// ------------------------------------------------- GEMM + el/er (per layer)
__global__ __launch_bounds__(256) void gemm_el_er(const float* __restrict__ H,
                                                  const float* __restrict__ W,
                                                  const float* __restrict__ al,
                                                  const float* __restrict__ ar,
                                                  float* __restrict__ feat,
                                                  float* __restrict__ el,
                                                  float* __restrict__ er) {
    __shared__ float hs[NROWS][FDIM];
    const int t = threadIdx.x;
    const int r0 = blockIdx.x * NROWS;
    for (int r = 0; r < NROWS; r++) hs[r][t] = H[(size_t)(r0 + r) * FDIM + t];
    __syncthreads();

    const int wave = t >> 6;
    const int lane = t & 63;
    const int c0 = lane * 4;
    const int rbase = wave * 4;

    float acc[4][4] = {};
    for (int k = 0; k < FDIM; k += 4) {
        float4 w0 = *(const float4*)&W[(k + 0) * FDIM + c0];
        float4 w1 = *(const float4*)&W[(k + 1) * FDIM + c0];
        float4 w2 = *(const float4*)&W[(k + 2) * FDIM + c0];
        float4 w3 = *(const float4*)&W[(k + 3) * FDIM + c0];
#pragma unroll
        for (int r = 0; r < 4; r++) {
            float4 h4 = *(const float4*)&hs[rbase + r][k];
            acc[r][0] += h4.x * w0.x + h4.y * w1.x + h4.z * w2.x + h4.w * w3.x;
            acc[r][1] += h4.x * w0.y + h4.y * w1.y + h4.z * w2.y + h4.w * w3.y;
            acc[r][2] += h4.x * w0.z + h4.y * w1.z + h4.z * w2.z + h4.w * w3.z;
            acc[r][3] += h4.x * w0.w + h4.y * w1.w + h4.z * w2.w + h4.w * w3.w;
        }
    }

    const float4 alv = *(const float4*)&al[c0];
    const float4 arv = *(const float4*)&ar[c0];
    const int head = lane >> 4;

#pragma unroll
    for (int r = 0; r < 4; r++) {
        int n = r0 + rbase + r;
        float4 v = make_float4(acc[r][0], acc[r][1], acc[r][2], acc[r][3]);
        *(float4*)&feat[(size_t)n * FDIM + c0] = v;
        float pl = acc[r][0] * alv.x + acc[r][1] * alv.y + acc[r][2] * alv.z + acc[r][3] * alv.w;
        float pr = acc[r][0] * arv.x + acc[r][1] * arv.y + acc[r][2] * arv.z + acc[r][3] * arv.w;
        for (int off = 8; off; off >>= 1) {
            pl += __shfl_down(pl, off, 16);
            pr += __shfl_down(pr, off, 16);
        }
        if ((lane & 15) == 0) {
            el[n * HEADS + head] = pl;
            er[n * HEADS + head] = pr;
        }
    }
}

// --------------------------------------------- per-dst softmax stats (m, 1/s)
// One wave per node; lane = edge slot. Edge-parallel gathers of el + shuffle
// butterflies replace the old serial per-edge loops.
__global__ __launch_bounds__(256) void softmax_stats(const float* __restrict__ el,
                                                     const float* __restrict__ er,
                                                     const int* __restrict__ offs,
                                                     const int* __restrict__ csr_src,
                                                     float* __restrict__ marr,
                                                     float* __restrict__ inv_s) {
    const int wave = threadIdx.x >> 6;
    const int lane = threadIdx.x & 63;
    const int n = blockIdx.x * 4 + wave;
    if (n >= N_NODES) return;
    const int beg = offs[n];
    const int end = offs[n + 1];
    const float4 erv = *(const float4*)&er[n * 4];

    float4 m = make_float4(-1e30f, -1e30f, -1e30f, -1e30f);
    for (int i = beg + lane; i < end; i += 64) {
        int s = csr_src[i];
        float4 e = *(const float4*)&el[s * 4];
        e.x += erv.x; e.y += erv.y; e.z += erv.z; e.w += erv.w;
        e.x = (e.x > 0.f) ? e.x : 0.2f * e.x;
        e.y = (e.y > 0.f) ? e.y : 0.2f * e.y;
        e.z = (e.z > 0.f) ? e.z : 0.2f * e.z;
        e.w = (e.w > 0.f) ? e.w : 0.2f * e.w;
        m.x = fmaxf(m.x, e.x); m.y = fmaxf(m.y, e.y);
        m.z = fmaxf(m.z, e.z); m.w = fmaxf(m.w, e.w);
    }
#pragma unroll
    for (int off = 32; off; off >>= 1) {
        m.x = fmaxf(m.x, __shfl_xor(m.x, off));
        m.y = fmaxf(m.y, __shfl_xor(m.y, off));
        m.z = fmaxf(m.z, __shfl_xor(m.z, off));
        m.w = fmaxf(m.w, __shfl_xor(m.w, off));
    }

    float4 ssum = make_float4(0.f, 0.f, 0.f, 0.f);
    for (int i = beg + lane; i < end; i += 64) {
        int s = csr_src[i];
        float4 e = *(const float4*)&el[s * 4];
        e.x += erv.x; e.y += erv.y; e.z += erv.z; e.w += erv.w;
        e.x = (e.x > 0.f) ? e.x : 0.2f * e.x;
        e.y = (e.y > 0.f) ? e.y : 0.2f * e.y;
        e.z = (e.z > 0.f) ? e.z : 0.2f * e.z;
        e.w = (e.w > 0.f) ? e.w : 0.2f * e.w;
        ssum.x += __expf(e.x - m.x);
        ssum.y += __expf(e.y - m.y);
        ssum.z += __expf(e.z - m.z);
        ssum.w += __expf(e.w - m.w);
    }
#pragma unroll
    for (int off = 32; off; off >>= 1) {
        ssum.x += __shfl_xor(ssum.x, off);
        ssum.y += __shfl_xor(ssum.y, off);
        ssum.z += __shfl_xor(ssum.z, off);
        ssum.w += __shfl_xor(ssum.w, off);
    }

    if (lane == 0) {
        *(float4*)&marr[n * 4] = m;
        float4 is = make_float4(1.f / fmaxf(ssum.x, 1e-9f), 1.f / fmaxf(ssum.y, 1e-9f),
                                1.f / fmaxf(ssum.z, 1e-9f), 1.f / fmaxf(ssum.w, 1e-9f));
        *(float4*)&inv_s[n * 4] = is;
    }
}

// ------------------------------------------- weighted aggregate (4 edges/iter)
// One block per node. Wave w handles edges beg+w, beg+w+4, ...; lane covers
// features lane*4..lane*4+3 via float4 (head = lane>>4). Cross-wave LDS sum.
__global__ __launch_bounds__(256) void aggregate2(const float* __restrict__ feat,
                                                  const float* __restrict__ el,
                                                  const float* __restrict__ er,
                                                  const float* __restrict__ marr,
                                                  const float* __restrict__ inv_s,
                                                  const float* __restrict__ bias,
                                                  const int* __restrict__ offs,
                                                  const int* __restrict__ csr_src,
                                                  float* __restrict__ out,
                                                  int head_major) {
    __shared__ float red[4][FDIM];
    const int n = blockIdx.x;
    const int t = threadIdx.x;
    const int wave = t >> 6;
    const int lane = t & 63;
    const int head = lane >> 4;
    const int beg = offs[n];
    const int end = offs[n + 1];

    const float er_h = er[n * 4 + head];
    const float m_h = marr[n * 4 + head];

    float4 acc = make_float4(0.f, 0.f, 0.f, 0.f);
    for (int i = beg + wave; i < end; i += 4) {
        int s = csr_src[i];
        float e = el[s * 4 + head] + er_h;
        e = (e > 0.f) ? e : 0.2f * e;
        float a = __expf(e - m_h);
        float4 f4 = *(const float4*)&feat[(size_t)s * FDIM + lane * 4];
        acc.x += a * f4.x; acc.y += a * f4.y; acc.z += a * f4.z; acc.w += a * f4.w;
    }
    *(float4*)&red[wave][lane * 4] = acc;
    __syncthreads();

    // thread t owns feature f = t
    const int f = t;
    const int fh = f >> 6;      // head of this feature
    const int d = f & 63;
    float ssum = red[0][f] + red[1][f] + red[2][f] + red[3][f];
    float r = ssum * inv_s[n * 4 + fh] + bias[f];
    r = (r > 0.f) ? r : expm1f(r);
    size_t oidx = head_major ? ((size_t)fh * N_NODES * HID + (size_t)n * HID + d)
                             : ((size_t)n * FDIM + f);
    out[oidx] = r;
}

// ---------------------------------------------------------------- launch

extern "C" void kernel_launch(void* const* d_in, const int* in_sizes, int n_in,
                              void* d_out, int out_size, void* d_ws, size_t ws_size,
                              hipStream_t stream) {
    const float* x   = (const float*)d_in[0];
    const int*   src = (const int*)d_in[1];
    const int*   dst = (const int*)d_in[2];
    const float* W0  = (const float*)d_in[3];
    const float* al0 = (const float*)d_in[4];
    const float* ar0 = (const float*)d_in[5];
    const float* b0  = (const float*)d_in[6];
    const float* W1  = (const float*)d_in[7];
    const float* al1 = (const float*)d_in[8];
    const float* ar1 = (const float*)d_in[9];
    const float* b1  = (const float*)d_in[10];
    float* out = (float*)d_out;

    // workspace layout (fp32 words)
    float* feat  = (float*)d_ws;                       // N*256
    float* el    = feat + (size_t)N_NODES * FDIM;      // N*4
    float* er    = el + N_NODES * HEADS;               // N*4
    float* marr  = er + N_NODES * HEADS;               // N*4
    float* inv_s = marr + N_NODES * HEADS;             // N*4
    int* counts  = (int*)(inv_s + N_NODES * HEADS);    // N
    int* cursor  = counts + N_NODES;                   // N
    int* offs    = cursor + N_NODES;                   // N+1
    int* csr_src = offs + (N_NODES + 1);               // E

    // ---- CSR build (graph identical for both layers)
    hipMemsetAsync(counts, 0, 2 * N_NODES * sizeof(int), stream);  // counts + cursor
    hist_kernel<<<(N_EDGES + 255) / 256, 256, 0, stream>>>(dst, counts, N_EDGES);
    scan_kernel<<<1, 1024, 0, stream>>>(counts, offs, N_NODES);
    scatter_kernel<<<(N_EDGES + 255) / 256, 256, 0, stream>>>(src, dst, offs, cursor, csr_src, N_EDGES);

    // ---- layer 1 (hidden h1 stored in d_out as [N,256])
    gemm_el_er<<<N_NODES / NROWS, 256, 0, stream>>>(x, W0, al0, ar0, feat, el, er);
    softmax_stats<<<(N_NODES + 3) / 4, 256, 0, stream>>>(el, er, offs, csr_src, marr, inv_s);
    aggregate2<<<N_NODES, 256, 0, stream>>>(feat, el, er, marr, inv_s, b0, offs, csr_src, out, 0);

    // ---- layer 2 (reads h1 from d_out, final write head-major over d_out)
    gemm_el_er<<<N_NODES / NROWS, 256, 0, stream>>>(out, W1, al1, ar1, feat, el, er);
    softmax_stats<<<(N_NODES + 3) / 4, 256, 0, stream>>>(el, er, offs, csr_src, marr, inv_s);
    aggregate2<<<N_NODES, 256, 0, stream>>>(feat, el, er, marr, inv_s, b1, offs, csr_src, out, 1);
}

// Round 3
// 664.757 us; speedup vs baseline: 1.5759x; 1.2246x over previous
//
#include <hip/hip_runtime.h>
#include <math.h>

#define N_NODES 50000
#define N_EDGES 800000
#define HEADS 4
#define HID 64
#define FDIM 256      // HEADS*HID == F_IN == 256 for both layers
#define LDA 40        // padded LDS k-stride (ushort elems): 80B row stride

typedef __attribute__((ext_vector_type(8))) short short8;
typedef __attribute__((ext_vector_type(4))) float f32x4;
typedef __attribute__((ext_vector_type(4))) unsigned short ushort4v;

// bf16 helpers (bit-level, RNE) — avoids __bf16-type/builtin signature risk
__device__ __forceinline__ unsigned short f2bf(float f) {
    union { float f; unsigned int u; } c; c.f = f;
    unsigned int u = c.u;
    u += 0x7FFFu + ((u >> 16) & 1u);
    return (unsigned short)(u >> 16);
}
__device__ __forceinline__ float bf2f(unsigned short b) {
    union { unsigned int u; float f; } c; c.u = ((unsigned int)b) << 16;
    return c.f;
}

// ---------------------------------------------------------------- CSR build

__global__ __launch_bounds__(256) void hist_kernel(const int* __restrict__ dst,
                                                   int* __restrict__ counts, int E) {
    int i = blockIdx.x * blockDim.x + threadIdx.x;
    if (i < E) atomicAdd(&counts[dst[i]], 1);
}

__global__ __launch_bounds__(1024) void scan_kernel(const int* __restrict__ counts,
                                                    int* __restrict__ offs, int n) {
    __shared__ int partial[1024];
    int t = threadIdx.x;
    int chunk = (n + 1023) / 1024;
    int lo = t * chunk;
    int hi = lo + chunk; if (hi > n) hi = n;
    int s = 0;
    for (int i = lo; i < hi; i++) s += counts[i];
    partial[t] = s;
    __syncthreads();
    for (int off = 1; off < 1024; off <<= 1) {
        int v = 0;
        if (t >= off) v = partial[t - off];
        __syncthreads();
        if (t >= off) partial[t] += v;
        __syncthreads();
    }
    int run = (t > 0) ? partial[t - 1] : 0;
    for (int i = lo; i < hi; i++) { offs[i] = run; run += counts[i]; }
    if (t == 1023) offs[n] = partial[1023];
}

__global__ __launch_bounds__(256) void scatter_kernel(const int* __restrict__ src,
                                                      const int* __restrict__ dst,
                                                      const int* __restrict__ offs,
                                                      int* __restrict__ cursor,
                                                      int* __restrict__ csr_src, int E) {
    int i = blockIdx.x * blockDim.x + threadIdx.x;
    if (i < E) {
        int d = dst[i];
        int p = offs[d] + atomicAdd(&cursor[d], 1);
        csr_src[p] = src[i];
    }
}

// -------------------------------------------- W prep: split + transpose
// Bt[n][k] = W[k][n] split into bf16 hi/lo. One kernel does both layers.
__global__ __launch_bounds__(256) void wsplit_kernel(const float* __restrict__ W0,
                                                     const float* __restrict__ W1,
                                                     unsigned short* __restrict__ bt0h,
                                                     unsigned short* __restrict__ bt0l,
                                                     unsigned short* __restrict__ bt1h,
                                                     unsigned short* __restrict__ bt1l) {
    const float* W = blockIdx.y ? W1 : W0;
    unsigned short* bh = blockIdx.y ? bt1h : bt0h;
    unsigned short* bl = blockIdx.y ? bt1l : bt0l;
    int n = blockIdx.x * 16 + (threadIdx.x >> 4);
    int k0 = (threadIdx.x & 15) * 16;
    for (int j = 0; j < 16; j++) {
        float w = W[(k0 + j) * FDIM + n];
        unsigned short h = f2bf(w);
        bh[n * FDIM + k0 + j] = h;
        bl[n * FDIM + k0 + j] = f2bf(w - bf2f(h));
    }
}

// -------------------------------------------- split-bf16 MFMA GEMM
// C[M,256] = A[M,256] @ W[256,256], W given pre-split/transposed as Bt[n][k].
// Block tile 128x128, 4 waves each own a 64x64 quadrant (4x4 of 16x16x32).
// C = Ah*Bh + Al*Bh + Ah*Bl  (lo*lo dropped, ~2^-18 relative)
__global__ __launch_bounds__(256) void mfma_gemm(const float* __restrict__ A,
                                                 const unsigned short* __restrict__ Bth,
                                                 const unsigned short* __restrict__ Btl,
                                                 float* __restrict__ C) {
    __shared__ unsigned short ash[128][LDA];
    __shared__ unsigned short asl[128][LDA];
    __shared__ unsigned short bsh[128][LDA];
    __shared__ unsigned short bsl[128][LDA];

    const int t = threadIdx.x;
    const int m0 = blockIdx.x * 128;
    const int n0 = blockIdx.y * 128;
    const int wave = t >> 6, lane = t & 63;
    const int quad = lane >> 4, l16 = lane & 15;
    const int wr = (wave >> 1) * 64;   // wave row offset within tile
    const int wc = (wave & 1) * 64;    // wave col offset within tile

    const f32x4 zero = {0.f, 0.f, 0.f, 0.f};
    f32x4 acc[4][4];
#pragma unroll
    for (int i = 0; i < 4; i++)
#pragma unroll
        for (int j = 0; j < 4; j++) acc[i][j] = zero;

    const int ar = t >> 3;             // A staging: base row (0..31)
    const int ac = (t & 7) * 4;        // A staging: col (float4)

    for (int kk = 0; kk < FDIM; kk += 32) {
        // ---- stage A tile (fp32 -> hi/lo bf16 at staging time)
#pragma unroll
        for (int rr = 0; rr < 4; rr++) {
            int row = ar + rr * 32;
            int gr = m0 + row; if (gr >= N_NODES) gr = N_NODES - 1;
            float4 v = *(const float4*)&A[(size_t)gr * FDIM + kk + ac];
            unsigned short h0 = f2bf(v.x), h1 = f2bf(v.y), h2 = f2bf(v.z), h3 = f2bf(v.w);
            ushort4v hv = {h0, h1, h2, h3};
            ushort4v lv = {f2bf(v.x - bf2f(h0)), f2bf(v.y - bf2f(h1)),
                           f2bf(v.z - bf2f(h2)), f2bf(v.w - bf2f(h3))};
            *(ushort4v*)&ash[row][ac] = hv;
            *(ushort4v*)&asl[row][ac] = lv;
        }
        // ---- stage B tiles (already bf16, 16B chunks)
#pragma unroll
        for (int ii = 0; ii < 2; ii++) {
            int idx = t + ii * 256;
            int row = idx >> 2;          // n within tile (0..127)
            int kb = (idx & 3) * 8;      // k elem offset (0,8,16,24)
            const short8 gh = *(const short8*)&Bth[(size_t)(n0 + row) * FDIM + kk + kb];
            const short8 gl = *(const short8*)&Btl[(size_t)(n0 + row) * FDIM + kk + kb];
            *(short8*)&bsh[row][kb] = gh;
            *(short8*)&bsl[row][kb] = gl;
        }
        __syncthreads();

        // ---- fragments + MFMA
        short8 ah[4], al_[4], bh[4], bl[4];
#pragma unroll
        for (int i = 0; i < 4; i++) {
            ah[i]  = *(short8*)&ash[wr + i * 16 + l16][quad * 8];
            al_[i] = *(short8*)&asl[wr + i * 16 + l16][quad * 8];
            bh[i]  = *(short8*)&bsh[wc + i * 16 + l16][quad * 8];
            bl[i]  = *(short8*)&bsl[wc + i * 16 + l16][quad * 8];
        }
#pragma unroll
        for (int mt = 0; mt < 4; mt++)
#pragma unroll
            for (int nt = 0; nt < 4; nt++) {
                f32x4 c = acc[mt][nt];
                c = __builtin_amdgcn_mfma_f32_16x16x32_bf16(ah[mt], bh[nt], c, 0, 0, 0);
                c = __builtin_amdgcn_mfma_f32_16x16x32_bf16(al_[mt], bh[nt], c, 0, 0, 0);
                c = __builtin_amdgcn_mfma_f32_16x16x32_bf16(ah[mt], bl[nt], c, 0, 0, 0);
                acc[mt][nt] = c;
            }
        __syncthreads();
    }

    // ---- epilogue: C/D layout col=lane&15, row=quad*4+reg
#pragma unroll
    for (int mt = 0; mt < 4; mt++) {
        int m = m0 + wr + mt * 16 + quad * 4;
#pragma unroll
        for (int nt = 0; nt < 4; nt++) {
            int n = n0 + wc + nt * 16 + l16;
#pragma unroll
            for (int r = 0; r < 4; r++) {
                if (m + r < N_NODES) C[(size_t)(m + r) * FDIM + n] = acc[mt][nt][r];
            }
        }
    }
}

// -------------------------------------------- el/er from feat (wave per node)
__global__ __launch_bounds__(256) void el_er_kernel(const float* __restrict__ feat,
                                                    const float* __restrict__ al,
                                                    const float* __restrict__ ar,
                                                    float* __restrict__ el,
                                                    float* __restrict__ er) {
    const int wave = threadIdx.x >> 6, lane = threadIdx.x & 63;
    const int n = blockIdx.x * 4 + wave;
    if (n >= N_NODES) return;
    float4 f = *(const float4*)&feat[(size_t)n * FDIM + lane * 4];
    float4 a = *(const float4*)&al[lane * 4];
    float4 b = *(const float4*)&ar[lane * 4];
    float pl = f.x * a.x + f.y * a.y + f.z * a.z + f.w * a.w;
    float pr = f.x * b.x + f.y * b.y + f.z * b.z + f.w * b.w;
    for (int off = 8; off; off >>= 1) {
        pl += __shfl_down(pl, off, 16);
        pr += __shfl_down(pr, off, 16);
    }
    if ((lane & 15) == 0) {
        el[n * HEADS + (lane >> 4)] = pl;
        er[n * HEADS + (lane >> 4)] = pr;
    }
}

// --------------------------------------------- per-dst softmax stats (m, 1/s)
__global__ __launch_bounds__(256) void softmax_stats(const float* __restrict__ el,
                                                     const float* __restrict__ er,
                                                     const int* __restrict__ offs,
                                                     const int* __restrict__ csr_src,
                                                     float* __restrict__ marr,
                                                     float* __restrict__ inv_s) {
    const int wave = threadIdx.x >> 6;
    const int lane = threadIdx.x & 63;
    const int n = blockIdx.x * 4 + wave;
    if (n >= N_NODES) return;
    const int beg = offs[n];
    const int end = offs[n + 1];
    const float4 erv = *(const float4*)&er[n * 4];

    float4 m = make_float4(-1e30f, -1e30f, -1e30f, -1e30f);
    for (int i = beg + lane; i < end; i += 64) {
        int s = csr_src[i];
        float4 e = *(const float4*)&el[s * 4];
        e.x += erv.x; e.y += erv.y; e.z += erv.z; e.w += erv.w;
        e.x = (e.x > 0.f) ? e.x : 0.2f * e.x;
        e.y = (e.y > 0.f) ? e.y : 0.2f * e.y;
        e.z = (e.z > 0.f) ? e.z : 0.2f * e.z;
        e.w = (e.w > 0.f) ? e.w : 0.2f * e.w;
        m.x = fmaxf(m.x, e.x); m.y = fmaxf(m.y, e.y);
        m.z = fmaxf(m.z, e.z); m.w = fmaxf(m.w, e.w);
    }
#pragma unroll
    for (int off = 32; off; off >>= 1) {
        m.x = fmaxf(m.x, __shfl_xor(m.x, off));
        m.y = fmaxf(m.y, __shfl_xor(m.y, off));
        m.z = fmaxf(m.z, __shfl_xor(m.z, off));
        m.w = fmaxf(m.w, __shfl_xor(m.w, off));
    }

    float4 ssum = make_float4(0.f, 0.f, 0.f, 0.f);
    for (int i = beg + lane; i < end; i += 64) {
        int s = csr_src[i];
        float4 e = *(const float4*)&el[s * 4];
        e.x += erv.x; e.y += erv.y; e.z += erv.z; e.w += erv.w;
        e.x = (e.x > 0.f) ? e.x : 0.2f * e.x;
        e.y = (e.y > 0.f) ? e.y : 0.2f * e.y;
        e.z = (e.z > 0.f) ? e.z : 0.2f * e.z;
        e.w = (e.w > 0.f) ? e.w : 0.2f * e.w;
        ssum.x += __expf(e.x - m.x);
        ssum.y += __expf(e.y - m.y);
        ssum.z += __expf(e.z - m.z);
        ssum.w += __expf(e.w - m.w);
    }
#pragma unroll
    for (int off = 32; off; off >>= 1) {
        ssum.x += __shfl_xor(ssum.x, off);
        ssum.y += __shfl_xor(ssum.y, off);
        ssum.z += __shfl_xor(ssum.z, off);
        ssum.w += __shfl_xor(ssum.w, off);
    }

    if (lane == 0) {
        *(float4*)&marr[n * 4] = m;
        float4 is = make_float4(1.f / fmaxf(ssum.x, 1e-9f), 1.f / fmaxf(ssum.y, 1e-9f),
                                1.f / fmaxf(ssum.z, 1e-9f), 1.f / fmaxf(ssum.w, 1e-9f));
        *(float4*)&inv_s[n * 4] = is;
    }
}

// ------------------------------------------- weighted aggregate (4 edges/iter)
__global__ __launch_bounds__(256) void aggregate2(const float* __restrict__ feat,
                                                  const float* __restrict__ el,
                                                  const float* __restrict__ er,
                                                  const float* __restrict__ marr,
                                                  const float* __restrict__ inv_s,
                                                  const float* __restrict__ bias,
                                                  const int* __restrict__ offs,
                                                  const int* __restrict__ csr_src,
                                                  float* __restrict__ out,
                                                  int head_major) {
    __shared__ float red[4][FDIM];
    const int n = blockIdx.x;
    const int t = threadIdx.x;
    const int wave = t >> 6;
    const int lane = t & 63;
    const int head = lane >> 4;
    const int beg = offs[n];
    const int end = offs[n + 1];

    const float er_h = er[n * 4 + head];
    const float m_h = marr[n * 4 + head];

    float4 acc = make_float4(0.f, 0.f, 0.f, 0.f);
    for (int i = beg + wave; i < end; i += 4) {
        int s = csr_src[i];
        float e = el[s * 4 + head] + er_h;
        e = (e > 0.f) ? e : 0.2f * e;
        float a = __expf(e - m_h);
        float4 f4 = *(const float4*)&feat[(size_t)s * FDIM + lane * 4];
        acc.x += a * f4.x; acc.y += a * f4.y; acc.z += a * f4.z; acc.w += a * f4.w;
    }
    *(float4*)&red[wave][lane * 4] = acc;
    __syncthreads();

    const int f = t;
    const int fh = f >> 6;
    const int d = f & 63;
    float ssum = red[0][f] + red[1][f] + red[2][f] + red[3][f];
    float r = ssum * inv_s[n * 4 + fh] + bias[f];
    r = (r > 0.f) ? r : expm1f(r);
    size_t oidx = head_major ? ((size_t)fh * N_NODES * HID + (size_t)n * HID + d)
                             : ((size_t)n * FDIM + f);
    out[oidx] = r;
}

// ---------------------------------------------------------------- launch

extern "C" void kernel_launch(void* const* d_in, const int* in_sizes, int n_in,
                              void* d_out, int out_size, void* d_ws, size_t ws_size,
                              hipStream_t stream) {
    const float* x   = (const float*)d_in[0];
    const int*   src = (const int*)d_in[1];
    const int*   dst = (const int*)d_in[2];
    const float* W0  = (const float*)d_in[3];
    const float* al0 = (const float*)d_in[4];
    const float* ar0 = (const float*)d_in[5];
    const float* b0  = (const float*)d_in[6];
    const float* W1  = (const float*)d_in[7];
    const float* al1 = (const float*)d_in[8];
    const float* ar1 = (const float*)d_in[9];
    const float* b1  = (const float*)d_in[10];
    float* out = (float*)d_out;

    // workspace layout
    float* feat  = (float*)d_ws;                       // N*256
    float* el    = feat + (size_t)N_NODES * FDIM;      // N*4
    float* er    = el + N_NODES * HEADS;               // N*4
    float* marr  = er + N_NODES * HEADS;               // N*4
    float* inv_s = marr + N_NODES * HEADS;             // N*4
    int* counts  = (int*)(inv_s + N_NODES * HEADS);    // N
    int* cursor  = counts + N_NODES;                   // N
    int* offs    = cursor + N_NODES;                   // N+1
    int* csr_src = offs + (N_NODES + 1);               // E
    unsigned short* bt0h = (unsigned short*)(csr_src + N_EDGES); // 256*256 each
    unsigned short* bt0l = bt0h + FDIM * FDIM;
    unsigned short* bt1h = bt0l + FDIM * FDIM;
    unsigned short* bt1l = bt1h + FDIM * FDIM;

    // ---- W prep + CSR build
    hipMemsetAsync(counts, 0, 2 * N_NODES * sizeof(int), stream);
    wsplit_kernel<<<dim3(16, 2), 256, 0, stream>>>(W0, W1, bt0h, bt0l, bt1h, bt1l);
    hist_kernel<<<(N_EDGES + 255) / 256, 256, 0, stream>>>(dst, counts, N_EDGES);
    scan_kernel<<<1, 1024, 0, stream>>>(counts, offs, N_NODES);
    scatter_kernel<<<(N_EDGES + 255) / 256, 256, 0, stream>>>(src, dst, offs, cursor, csr_src, N_EDGES);

    dim3 ggrid((N_NODES + 127) / 128, FDIM / 128);

    // ---- layer 1 (hidden h1 stored in d_out as [N,256] fp32)
    mfma_gemm<<<ggrid, 256, 0, stream>>>(x, bt0h, bt0l, feat);
    el_er_kernel<<<(N_NODES + 3) / 4, 256, 0, stream>>>(feat, al0, ar0, el, er);
    softmax_stats<<<(N_NODES + 3) / 4, 256, 0, stream>>>(el, er, offs, csr_src, marr, inv_s);
    aggregate2<<<N_NODES, 256, 0, stream>>>(feat, el, er, marr, inv_s, b0, offs, csr_src, out, 0);

    // ---- layer 2 (reads h1 from d_out, final write head-major over d_out)
    mfma_gemm<<<ggrid, 256, 0, stream>>>(out, bt1h, bt1l, feat);
    el_er_kernel<<<(N_NODES + 3) / 4, 256, 0, stream>>>(feat, al1, ar1, el, er);
    softmax_stats<<<(N_NODES + 3) / 4, 256, 0, stream>>>(el, er, offs, csr_src, marr, inv_s);
    aggregate2<<<N_NODES, 256, 0, stream>>>(feat, el, er, marr, inv_s, b1, offs, csr_src, out, 1);
}

// Round 4
// 500.874 us; speedup vs baseline: 2.0916x; 1.3272x over previous
//
#include <hip/hip_runtime.h>
#include <math.h>

#define N_NODES 50000
#define N_EDGES 800000
#define HEADS 4
#define HID 64
#define FDIM 256      // HEADS*HID == F_IN == 256 for both layers
#define LDA 40        // padded LDS k-stride (ushort elems): 80B row stride
#define SCAN_CHUNK 1024
#define SCAN_NB ((N_NODES + SCAN_CHUNK - 1) / SCAN_CHUNK)   // 49

typedef __attribute__((ext_vector_type(8))) short short8;
typedef __attribute__((ext_vector_type(4))) float f32x4;
typedef __attribute__((ext_vector_type(4))) unsigned short ushort4v;
typedef __attribute__((ext_vector_type(8))) _Float16 half8v;

// bf16 helpers (bit-level, RNE)
__device__ __forceinline__ unsigned short f2bf(float f) {
    union { float f; unsigned int u; } c; c.f = f;
    unsigned int u = c.u;
    u += 0x7FFFu + ((u >> 16) & 1u);
    return (unsigned short)(u >> 16);
}
__device__ __forceinline__ float bf2f(unsigned short b) {
    union { unsigned int u; float f; } c; c.u = ((unsigned int)b) << 16;
    return c.f;
}

// ---------------------------------------------------------------- CSR build

__global__ __launch_bounds__(256) void hist_kernel(const int* __restrict__ dst,
                                                   int* __restrict__ counts, int E) {
    int i = blockIdx.x * blockDim.x + threadIdx.x;
    if (i < E) atomicAdd(&counts[dst[i]], 1);
}

// exclusive scan, stage 1: per-1024-chunk local scan + block sums
__global__ __launch_bounds__(256) void scan_local(const int* __restrict__ counts,
                                                  int* __restrict__ offs,
                                                  int* __restrict__ bsum, int n) {
    __shared__ int part[256];
    const int b = blockIdx.x, t = threadIdx.x;
    const int base = b * SCAN_CHUNK + t * 4;
    int v[4];
#pragma unroll
    for (int j = 0; j < 4; j++) {
        int idx = base + j;
        v[j] = (idx < n) ? counts[idx] : 0;
    }
    int s0 = v[0], s1 = s0 + v[1], s2 = s1 + v[2], s3 = s2 + v[3];
    part[t] = s3;
    __syncthreads();
    for (int off = 1; off < 256; off <<= 1) {
        int x = (t >= off) ? part[t - off] : 0;
        __syncthreads();
        part[t] += x;
        __syncthreads();
    }
    int prefix = (t > 0) ? part[t - 1] : 0;
    int e[4] = {prefix, prefix + s0, prefix + s1, prefix + s2};
#pragma unroll
    for (int j = 0; j < 4; j++) {
        int idx = base + j;
        if (idx < n) offs[idx] = e[j];
    }
    if (t == 255) bsum[b] = part[255];
}

// stage 2: exclusive scan of the 49 block sums (one wave); writes offs[n]=total
__global__ __launch_bounds__(64) void scan_bsum(int* __restrict__ bsum,
                                                int* __restrict__ offs, int nb, int n) {
    int lane = threadIdx.x;
    int own = (lane < nb) ? bsum[lane] : 0;
    int v = own;
    for (int off = 1; off < 64; off <<= 1) {
        int x = __shfl_up(v, off);
        if (lane >= off) v += x;
    }
    if (lane < nb) bsum[lane] = v - own;   // exclusive prefix
    if (lane == nb - 1) offs[n] = v;       // grand total
}

// stage 3: add block prefix
__global__ __launch_bounds__(256) void scan_add(int* __restrict__ offs,
                                                const int* __restrict__ bsum, int n) {
    const int b = blockIdx.x;
    const int p = bsum[b];
    const int base = b * SCAN_CHUNK + threadIdx.x * 4;
#pragma unroll
    for (int j = 0; j < 4; j++) {
        int idx = base + j;
        if (idx < n) offs[idx] += p;
    }
}

__global__ __launch_bounds__(256) void scatter_kernel(const int* __restrict__ src,
                                                      const int* __restrict__ dst,
                                                      const int* __restrict__ offs,
                                                      int* __restrict__ cursor,
                                                      int* __restrict__ csr_src, int E) {
    int i = blockIdx.x * blockDim.x + threadIdx.x;
    if (i < E) {
        int d = dst[i];
        int p = offs[d] + atomicAdd(&cursor[d], 1);
        csr_src[p] = src[i];
    }
}

// -------------------------------------------- W prep: split + transpose
__global__ __launch_bounds__(256) void wsplit_kernel(const float* __restrict__ W0,
                                                     const float* __restrict__ W1,
                                                     unsigned short* __restrict__ bt0h,
                                                     unsigned short* __restrict__ bt0l,
                                                     unsigned short* __restrict__ bt1h,
                                                     unsigned short* __restrict__ bt1l) {
    const float* W = blockIdx.y ? W1 : W0;
    unsigned short* bh = blockIdx.y ? bt1h : bt0h;
    unsigned short* bl = blockIdx.y ? bt1l : bt0l;
    int n = blockIdx.x * 16 + (threadIdx.x >> 4);
    int k0 = (threadIdx.x & 15) * 16;
    for (int j = 0; j < 16; j++) {
        float w = W[(k0 + j) * FDIM + n];
        unsigned short h = f2bf(w);
        bh[n * FDIM + k0 + j] = h;
        bl[n * FDIM + k0 + j] = f2bf(w - bf2f(h));
    }
}

// -------------------------------------------- split-bf16 MFMA GEMM + el/er
// C = A @ W (W pre-split/transposed). Writes feat16 (fp16) and full el/er
// (each wave's 64-col quadrant == one head; width-16 shuffle completes the
// head-dim reduction, no atomics).
__global__ __launch_bounds__(256) void mfma_gemm(const float* __restrict__ A,
                                                 const unsigned short* __restrict__ Bth,
                                                 const unsigned short* __restrict__ Btl,
                                                 const float* __restrict__ al,
                                                 const float* __restrict__ ar,
                                                 _Float16* __restrict__ feat16,
                                                 float* __restrict__ el,
                                                 float* __restrict__ er) {
    __shared__ unsigned short ash[128][LDA];
    __shared__ unsigned short asl[128][LDA];
    __shared__ unsigned short bsh[128][LDA];
    __shared__ unsigned short bsl[128][LDA];

    const int t = threadIdx.x;
    const int m0 = blockIdx.x * 128;
    const int n0 = blockIdx.y * 128;
    const int wave = t >> 6, lane = t & 63;
    const int quad = lane >> 4, l16 = lane & 15;
    const int wr = (wave >> 1) * 64;
    const int wc = (wave & 1) * 64;

    const f32x4 zero = {0.f, 0.f, 0.f, 0.f};
    f32x4 acc[4][4];
#pragma unroll
    for (int i = 0; i < 4; i++)
#pragma unroll
        for (int j = 0; j < 4; j++) acc[i][j] = zero;

    const int ar_ = t >> 3;
    const int ac = (t & 7) * 4;

    for (int kk = 0; kk < FDIM; kk += 32) {
#pragma unroll
        for (int rr = 0; rr < 4; rr++) {
            int row = ar_ + rr * 32;
            int gr = m0 + row; if (gr >= N_NODES) gr = N_NODES - 1;
            float4 v = *(const float4*)&A[(size_t)gr * FDIM + kk + ac];
            unsigned short h0 = f2bf(v.x), h1 = f2bf(v.y), h2 = f2bf(v.z), h3 = f2bf(v.w);
            ushort4v hv = {h0, h1, h2, h3};
            ushort4v lv = {f2bf(v.x - bf2f(h0)), f2bf(v.y - bf2f(h1)),
                           f2bf(v.z - bf2f(h2)), f2bf(v.w - bf2f(h3))};
            *(ushort4v*)&ash[row][ac] = hv;
            *(ushort4v*)&asl[row][ac] = lv;
        }
#pragma unroll
        for (int ii = 0; ii < 2; ii++) {
            int idx = t + ii * 256;
            int row = idx >> 2;
            int kb = (idx & 3) * 8;
            const short8 gh = *(const short8*)&Bth[(size_t)(n0 + row) * FDIM + kk + kb];
            const short8 gl = *(const short8*)&Btl[(size_t)(n0 + row) * FDIM + kk + kb];
            *(short8*)&bsh[row][kb] = gh;
            *(short8*)&bsl[row][kb] = gl;
        }
        __syncthreads();

        short8 ah[4], alo[4], bh[4], bl[4];
#pragma unroll
        for (int i = 0; i < 4; i++) {
            ah[i]  = *(short8*)&ash[wr + i * 16 + l16][quad * 8];
            alo[i] = *(short8*)&asl[wr + i * 16 + l16][quad * 8];
            bh[i]  = *(short8*)&bsh[wc + i * 16 + l16][quad * 8];
            bl[i]  = *(short8*)&bsl[wc + i * 16 + l16][quad * 8];
        }
#pragma unroll
        for (int mt = 0; mt < 4; mt++)
#pragma unroll
            for (int nt = 0; nt < 4; nt++) {
                f32x4 c = acc[mt][nt];
                c = __builtin_amdgcn_mfma_f32_16x16x32_bf16(ah[mt], bh[nt], c, 0, 0, 0);
                c = __builtin_amdgcn_mfma_f32_16x16x32_bf16(alo[mt], bh[nt], c, 0, 0, 0);
                c = __builtin_amdgcn_mfma_f32_16x16x32_bf16(ah[mt], bl[nt], c, 0, 0, 0);
                acc[mt][nt] = c;
            }
        __syncthreads();
    }

    // ---- epilogue: feat16 store + fused el/er (this wave's head = h)
    const int h = (n0 + wc) >> 6;
    float alv[4], arv[4];
#pragma unroll
    for (int nt = 0; nt < 4; nt++) {
        alv[nt] = al[n0 + wc + nt * 16 + l16];
        arv[nt] = ar[n0 + wc + nt * 16 + l16];
    }
#pragma unroll
    for (int mt = 0; mt < 4; mt++) {
        int m = m0 + wr + mt * 16 + quad * 4;
        float pl[4] = {0.f, 0.f, 0.f, 0.f}, pr[4] = {0.f, 0.f, 0.f, 0.f};
#pragma unroll
        for (int nt = 0; nt < 4; nt++) {
            int n = n0 + wc + nt * 16 + l16;
#pragma unroll
            for (int r = 0; r < 4; r++) {
                float v = acc[mt][nt][r];
                if (m + r < N_NODES) feat16[(size_t)(m + r) * FDIM + n] = (_Float16)v;
                pl[r] += v * alv[nt];
                pr[r] += v * arv[nt];
            }
        }
#pragma unroll
        for (int r = 0; r < 4; r++) {
            float a = pl[r], b = pr[r];
            for (int off = 8; off; off >>= 1) {
                a += __shfl_down(a, off, 16);
                b += __shfl_down(b, off, 16);
            }
            if (l16 == 0 && m + r < N_NODES) {
                el[(m + r) * 4 + h] = a;
                er[(m + r) * 4 + h] = b;
            }
        }
    }
}

// --------------------------------------------- per-dst softmax stats (m, 1/s)
__global__ __launch_bounds__(256) void softmax_stats(const float* __restrict__ el,
                                                     const float* __restrict__ er,
                                                     const int* __restrict__ offs,
                                                     const int* __restrict__ csr_src,
                                                     float* __restrict__ marr,
                                                     float* __restrict__ inv_s) {
    const int wave = threadIdx.x >> 6;
    const int lane = threadIdx.x & 63;
    const int n = blockIdx.x * 4 + wave;
    if (n >= N_NODES) return;
    const int beg = offs[n];
    const int end = offs[n + 1];
    const float4 erv = *(const float4*)&er[n * 4];

    float4 m = make_float4(-1e30f, -1e30f, -1e30f, -1e30f);
    for (int i = beg + lane; i < end; i += 64) {
        int s = csr_src[i];
        float4 e = *(const float4*)&el[s * 4];
        e.x += erv.x; e.y += erv.y; e.z += erv.z; e.w += erv.w;
        e.x = (e.x > 0.f) ? e.x : 0.2f * e.x;
        e.y = (e.y > 0.f) ? e.y : 0.2f * e.y;
        e.z = (e.z > 0.f) ? e.z : 0.2f * e.z;
        e.w = (e.w > 0.f) ? e.w : 0.2f * e.w;
        m.x = fmaxf(m.x, e.x); m.y = fmaxf(m.y, e.y);
        m.z = fmaxf(m.z, e.z); m.w = fmaxf(m.w, e.w);
    }
#pragma unroll
    for (int off = 32; off; off >>= 1) {
        m.x = fmaxf(m.x, __shfl_xor(m.x, off));
        m.y = fmaxf(m.y, __shfl_xor(m.y, off));
        m.z = fmaxf(m.z, __shfl_xor(m.z, off));
        m.w = fmaxf(m.w, __shfl_xor(m.w, off));
    }

    float4 ssum = make_float4(0.f, 0.f, 0.f, 0.f);
    for (int i = beg + lane; i < end; i += 64) {
        int s = csr_src[i];
        float4 e = *(const float4*)&el[s * 4];
        e.x += erv.x; e.y += erv.y; e.z += erv.z; e.w += erv.w;
        e.x = (e.x > 0.f) ? e.x : 0.2f * e.x;
        e.y = (e.y > 0.f) ? e.y : 0.2f * e.y;
        e.z = (e.z > 0.f) ? e.z : 0.2f * e.z;
        e.w = (e.w > 0.f) ? e.w : 0.2f * e.w;
        ssum.x += __expf(e.x - m.x);
        ssum.y += __expf(e.y - m.y);
        ssum.z += __expf(e.z - m.z);
        ssum.w += __expf(e.w - m.w);
    }
#pragma unroll
    for (int off = 32; off; off >>= 1) {
        ssum.x += __shfl_xor(ssum.x, off);
        ssum.y += __shfl_xor(ssum.y, off);
        ssum.z += __shfl_xor(ssum.z, off);
        ssum.w += __shfl_xor(ssum.w, off);
    }

    if (lane == 0) {
        *(float4*)&marr[n * 4] = m;
        float4 is = make_float4(1.f / fmaxf(ssum.x, 1e-9f), 1.f / fmaxf(ssum.y, 1e-9f),
                                1.f / fmaxf(ssum.z, 1e-9f), 1.f / fmaxf(ssum.w, 1e-9f));
        *(float4*)&inv_s[n * 4] = is;
    }
}

// ------------------------------------------- weighted aggregate, fp16 messages
// One block per node. Each wave handles 2 edges/iter: half-wave = edge slot,
// 32 lanes x 8 fp16 features (16B load) cover all 256 features.
__global__ __launch_bounds__(256) void aggregate3(const _Float16* __restrict__ feat16,
                                                  const float* __restrict__ el,
                                                  const float* __restrict__ er,
                                                  const float* __restrict__ marr,
                                                  const float* __restrict__ inv_s,
                                                  const float* __restrict__ bias,
                                                  const int* __restrict__ offs,
                                                  const int* __restrict__ csr_src,
                                                  float* __restrict__ out,
                                                  int head_major) {
    __shared__ float red[4][FDIM];
    const int n = blockIdx.x;
    const int t = threadIdx.x;
    const int wave = t >> 6;
    const int lane = t & 63;
    const int half = lane >> 5;
    const int l32 = lane & 31;
    const int f0 = l32 * 8;
    const int hh = l32 >> 3;          // head of this lane's features
    const int beg = offs[n];
    const int end = offs[n + 1];

    const float er_h = er[n * 4 + hh];
    const float m_h = marr[n * 4 + hh];

    float acc[8] = {0.f, 0.f, 0.f, 0.f, 0.f, 0.f, 0.f, 0.f};
    for (int i = beg + wave * 2 + half; i < end; i += 8) {
        int s = csr_src[i];
        float e = el[s * 4 + hh] + er_h;
        e = (e > 0.f) ? e : 0.2f * e;
        float a = __expf(e - m_h);
        half8v hv = *(const half8v*)&feat16[(size_t)s * FDIM + f0];
#pragma unroll
        for (int j = 0; j < 8; j++) acc[j] += a * (float)hv[j];
    }
#pragma unroll
    for (int j = 0; j < 8; j++) acc[j] += __shfl_xor(acc[j], 32);
    if (lane < 32) {
        float4 v0 = make_float4(acc[0], acc[1], acc[2], acc[3]);
        float4 v1 = make_float4(acc[4], acc[5], acc[6], acc[7]);
        *(float4*)&red[wave][f0] = v0;
        *(float4*)&red[wave][f0 + 4] = v1;
    }
    __syncthreads();

    const int f = t;
    const int fh = f >> 6;
    const int d = f & 63;
    float ssum = red[0][f] + red[1][f] + red[2][f] + red[3][f];
    float r = ssum * inv_s[n * 4 + fh] + bias[f];
    r = (r > 0.f) ? r : expm1f(r);
    size_t oidx = head_major ? ((size_t)fh * N_NODES * HID + (size_t)n * HID + d)
                             : ((size_t)n * FDIM + f);
    out[oidx] = r;
}

// ---------------------------------------------------------------- launch

extern "C" void kernel_launch(void* const* d_in, const int* in_sizes, int n_in,
                              void* d_out, int out_size, void* d_ws, size_t ws_size,
                              hipStream_t stream) {
    const float* x   = (const float*)d_in[0];
    const int*   src = (const int*)d_in[1];
    const int*   dst = (const int*)d_in[2];
    const float* W0  = (const float*)d_in[3];
    const float* al0 = (const float*)d_in[4];
    const float* ar0 = (const float*)d_in[5];
    const float* b0  = (const float*)d_in[6];
    const float* W1  = (const float*)d_in[7];
    const float* al1 = (const float*)d_in[8];
    const float* ar1 = (const float*)d_in[9];
    const float* b1  = (const float*)d_in[10];
    float* out = (float*)d_out;

    // workspace layout
    _Float16* feat16 = (_Float16*)d_ws;                          // N*256 fp16
    unsigned short* bt0h = (unsigned short*)(feat16 + (size_t)N_NODES * FDIM);
    unsigned short* bt0l = bt0h + FDIM * FDIM;
    unsigned short* bt1h = bt0l + FDIM * FDIM;
    unsigned short* bt1l = bt1h + FDIM * FDIM;
    float* el    = (float*)(bt1l + FDIM * FDIM);                 // N*4
    float* er    = el + N_NODES * HEADS;                         // N*4
    float* marr  = er + N_NODES * HEADS;                         // N*4
    float* inv_s = marr + N_NODES * HEADS;                       // N*4
    int* counts  = (int*)(inv_s + N_NODES * HEADS);              // N
    int* cursor  = counts + N_NODES;                             // N
    int* offs    = cursor + N_NODES;                             // N+1 (pad 50016)
    int* bsum    = offs + 50016;                                 // 64
    int* csr_src = bsum + 64;                                    // E

    // ---- W prep + CSR build
    hipMemsetAsync(counts, 0, 2 * N_NODES * sizeof(int), stream);  // counts + cursor
    wsplit_kernel<<<dim3(16, 2), 256, 0, stream>>>(W0, W1, bt0h, bt0l, bt1h, bt1l);
    hist_kernel<<<(N_EDGES + 255) / 256, 256, 0, stream>>>(dst, counts, N_EDGES);
    scan_local<<<SCAN_NB, 256, 0, stream>>>(counts, offs, bsum, N_NODES);
    scan_bsum<<<1, 64, 0, stream>>>(bsum, offs, SCAN_NB, N_NODES);
    scan_add<<<SCAN_NB, 256, 0, stream>>>(offs, bsum, N_NODES);
    scatter_kernel<<<(N_EDGES + 255) / 256, 256, 0, stream>>>(src, dst, offs, cursor, csr_src, N_EDGES);

    dim3 ggrid((N_NODES + 127) / 128, FDIM / 128);

    // ---- layer 1 (hidden h1 stored in d_out as [N,256] fp32)
    mfma_gemm<<<ggrid, 256, 0, stream>>>(x, bt0h, bt0l, al0, ar0, feat16, el, er);
    softmax_stats<<<(N_NODES + 3) / 4, 256, 0, stream>>>(el, er, offs, csr_src, marr, inv_s);
    aggregate3<<<N_NODES, 256, 0, stream>>>(feat16, el, er, marr, inv_s, b0, offs, csr_src, out, 0);

    // ---- layer 2 (reads h1 from d_out, final write head-major over d_out)
    mfma_gemm<<<ggrid, 256, 0, stream>>>(out, bt1h, bt1l, al1, ar1, feat16, el, er);
    softmax_stats<<<(N_NODES + 3) / 4, 256, 0, stream>>>(el, er, offs, csr_src, marr, inv_s);
    aggregate3<<<N_NODES, 256, 0, stream>>>(feat16, el, er, marr, inv_s, b1, offs, csr_src, out, 1);
}

// Round 5
// 422.465 us; speedup vs baseline: 2.4798x; 1.1856x over previous
//
#include <hip/hip_runtime.h>
#include <math.h>

#define N_NODES 50000
#define N_EDGES 800000
#define HEADS 4
#define HID 64
#define FDIM 256      // HEADS*HID == F_IN == 256 for both layers
#define LDA 40        // padded LDS k-stride (ushort elems): 80B row stride
#define SCAN_CHUNK 1024
#define SCAN_NB ((N_NODES + SCAN_CHUNK - 1) / SCAN_CHUNK)   // 49

typedef __attribute__((ext_vector_type(8))) short short8;
typedef __attribute__((ext_vector_type(4))) float f32x4;
typedef __attribute__((ext_vector_type(4))) unsigned short ushort4v;
typedef __attribute__((ext_vector_type(8))) _Float16 half8v;

// bf16 helpers (bit-level, RNE)
__device__ __forceinline__ unsigned short f2bf(float f) {
    union { float f; unsigned int u; } c; c.f = f;
    unsigned int u = c.u;
    u += 0x7FFFu + ((u >> 16) & 1u);
    return (unsigned short)(u >> 16);
}
__device__ __forceinline__ float bf2f(unsigned short b) {
    union { unsigned int u; float f; } c; c.u = ((unsigned int)b) << 16;
    return c.f;
}

// ---------------------------------------------------------------- CSR build

__global__ __launch_bounds__(256) void hist_kernel(const int* __restrict__ dst,
                                                   int* __restrict__ counts, int E) {
    int i = blockIdx.x * blockDim.x + threadIdx.x;
    if (i < E) atomicAdd(&counts[dst[i]], 1);
}

__global__ __launch_bounds__(256) void scan_local(const int* __restrict__ counts,
                                                  int* __restrict__ offs,
                                                  int* __restrict__ bsum, int n) {
    __shared__ int part[256];
    const int b = blockIdx.x, t = threadIdx.x;
    const int base = b * SCAN_CHUNK + t * 4;
    int v[4];
#pragma unroll
    for (int j = 0; j < 4; j++) {
        int idx = base + j;
        v[j] = (idx < n) ? counts[idx] : 0;
    }
    int s0 = v[0], s1 = s0 + v[1], s2 = s1 + v[2], s3 = s2 + v[3];
    part[t] = s3;
    __syncthreads();
    for (int off = 1; off < 256; off <<= 1) {
        int x = (t >= off) ? part[t - off] : 0;
        __syncthreads();
        part[t] += x;
        __syncthreads();
    }
    int prefix = (t > 0) ? part[t - 1] : 0;
    int e[4] = {prefix, prefix + s0, prefix + s1, prefix + s2};
#pragma unroll
    for (int j = 0; j < 4; j++) {
        int idx = base + j;
        if (idx < n) offs[idx] = e[j];
    }
    if (t == 255) bsum[b] = part[255];
}

__global__ __launch_bounds__(64) void scan_bsum(int* __restrict__ bsum,
                                                int* __restrict__ offs, int nb, int n) {
    int lane = threadIdx.x;
    int own = (lane < nb) ? bsum[lane] : 0;
    int v = own;
    for (int off = 1; off < 64; off <<= 1) {
        int x = __shfl_up(v, off);
        if (lane >= off) v += x;
    }
    if (lane < nb) bsum[lane] = v - own;   // exclusive prefix
    if (lane == nb - 1) offs[n] = v;       // grand total
}

__global__ __launch_bounds__(256) void scan_add(int* __restrict__ offs,
                                                const int* __restrict__ bsum, int n) {
    const int b = blockIdx.x;
    const int p = bsum[b];
    const int base = b * SCAN_CHUNK + threadIdx.x * 4;
#pragma unroll
    for (int j = 0; j < 4; j++) {
        int idx = base + j;
        if (idx < n) offs[idx] += p;
    }
}

__global__ __launch_bounds__(256) void scatter_kernel(const int* __restrict__ src,
                                                      const int* __restrict__ dst,
                                                      const int* __restrict__ offs,
                                                      int* __restrict__ cursor,
                                                      int* __restrict__ csr_src, int E) {
    int i = blockIdx.x * blockDim.x + threadIdx.x;
    if (i < E) {
        int d = dst[i];
        int p = offs[d] + atomicAdd(&cursor[d], 1);
        csr_src[p] = src[i];
    }
}

// -------------------------------------------- W prep: split + transpose
__global__ __launch_bounds__(256) void wsplit_kernel(const float* __restrict__ W0,
                                                     const float* __restrict__ W1,
                                                     unsigned short* __restrict__ bt0h,
                                                     unsigned short* __restrict__ bt0l,
                                                     unsigned short* __restrict__ bt1h,
                                                     unsigned short* __restrict__ bt1l) {
    const float* W = blockIdx.y ? W1 : W0;
    unsigned short* bh = blockIdx.y ? bt1h : bt0h;
    unsigned short* bl = blockIdx.y ? bt1l : bt0l;
    int n = blockIdx.x * 16 + (threadIdx.x >> 4);
    int k0 = (threadIdx.x & 15) * 16;
    for (int j = 0; j < 16; j++) {
        float w = W[(k0 + j) * FDIM + n];
        unsigned short h = f2bf(w);
        bh[n * FDIM + k0 + j] = h;
        bl[n * FDIM + k0 + j] = f2bf(w - bf2f(h));
    }
}

// -------------------------------------------- split-bf16 MFMA GEMM + el/er
// C = A @ W (W pre-split/transposed). PRESPLIT: A given as bf16 hi/lo arrays
// (no conversion in staging). Writes feat16 (fp16) + fused el/er.
template <bool PRESPLIT>
__global__ __launch_bounds__(256) void mfma_gemm(const float* __restrict__ A,
                                                 const unsigned short* __restrict__ Ah,
                                                 const unsigned short* __restrict__ Alo,
                                                 const unsigned short* __restrict__ Bth,
                                                 const unsigned short* __restrict__ Btl,
                                                 const float* __restrict__ al,
                                                 const float* __restrict__ ar,
                                                 _Float16* __restrict__ feat16,
                                                 float* __restrict__ el,
                                                 float* __restrict__ er) {
    __shared__ unsigned short ash[128][LDA];
    __shared__ unsigned short asl[128][LDA];
    __shared__ unsigned short bsh[128][LDA];
    __shared__ unsigned short bsl[128][LDA];

    const int t = threadIdx.x;
    const int m0 = blockIdx.x * 128;
    const int n0 = blockIdx.y * 128;
    const int wave = t >> 6, lane = t & 63;
    const int quad = lane >> 4, l16 = lane & 15;
    const int wr = (wave >> 1) * 64;
    const int wc = (wave & 1) * 64;

    const f32x4 zero = {0.f, 0.f, 0.f, 0.f};
    f32x4 acc[4][4];
#pragma unroll
    for (int i = 0; i < 4; i++)
#pragma unroll
        for (int j = 0; j < 4; j++) acc[i][j] = zero;

    const int ar_ = t >> 3;
    const int ac = (t & 7) * 4;

    for (int kk = 0; kk < FDIM; kk += 32) {
#pragma unroll
        for (int rr = 0; rr < 4; rr++) {
            int row = ar_ + rr * 32;
            int gr = m0 + row; if (gr >= N_NODES) gr = N_NODES - 1;
            if constexpr (PRESPLIT) {
                *(ushort4v*)&ash[row][ac] = *(const ushort4v*)&Ah[(size_t)gr * FDIM + kk + ac];
                *(ushort4v*)&asl[row][ac] = *(const ushort4v*)&Alo[(size_t)gr * FDIM + kk + ac];
            } else {
                float4 v = *(const float4*)&A[(size_t)gr * FDIM + kk + ac];
                unsigned short h0 = f2bf(v.x), h1 = f2bf(v.y), h2 = f2bf(v.z), h3 = f2bf(v.w);
                ushort4v hv = {h0, h1, h2, h3};
                ushort4v lv = {f2bf(v.x - bf2f(h0)), f2bf(v.y - bf2f(h1)),
                               f2bf(v.z - bf2f(h2)), f2bf(v.w - bf2f(h3))};
                *(ushort4v*)&ash[row][ac] = hv;
                *(ushort4v*)&asl[row][ac] = lv;
            }
        }
#pragma unroll
        for (int ii = 0; ii < 2; ii++) {
            int idx = t + ii * 256;
            int row = idx >> 2;
            int kb = (idx & 3) * 8;
            const short8 gh = *(const short8*)&Bth[(size_t)(n0 + row) * FDIM + kk + kb];
            const short8 gl = *(const short8*)&Btl[(size_t)(n0 + row) * FDIM + kk + kb];
            *(short8*)&bsh[row][kb] = gh;
            *(short8*)&bsl[row][kb] = gl;
        }
        __syncthreads();

        short8 ahf[4], alf[4], bhf[4], blf[4];
#pragma unroll
        for (int i = 0; i < 4; i++) {
            ahf[i] = *(short8*)&ash[wr + i * 16 + l16][quad * 8];
            alf[i] = *(short8*)&asl[wr + i * 16 + l16][quad * 8];
            bhf[i] = *(short8*)&bsh[wc + i * 16 + l16][quad * 8];
            blf[i] = *(short8*)&bsl[wc + i * 16 + l16][quad * 8];
        }
#pragma unroll
        for (int mt = 0; mt < 4; mt++)
#pragma unroll
            for (int nt = 0; nt < 4; nt++) {
                f32x4 c = acc[mt][nt];
                c = __builtin_amdgcn_mfma_f32_16x16x32_bf16(ahf[mt], bhf[nt], c, 0, 0, 0);
                c = __builtin_amdgcn_mfma_f32_16x16x32_bf16(alf[mt], bhf[nt], c, 0, 0, 0);
                c = __builtin_amdgcn_mfma_f32_16x16x32_bf16(ahf[mt], blf[nt], c, 0, 0, 0);
                acc[mt][nt] = c;
            }
        __syncthreads();
    }

    // ---- epilogue: feat16 store + fused el/er (this wave's head = h)
    const int h = (n0 + wc) >> 6;
    float alv[4], arv[4];
#pragma unroll
    for (int nt = 0; nt < 4; nt++) {
        alv[nt] = al[n0 + wc + nt * 16 + l16];
        arv[nt] = ar[n0 + wc + nt * 16 + l16];
    }
#pragma unroll
    for (int mt = 0; mt < 4; mt++) {
        int m = m0 + wr + mt * 16 + quad * 4;
        float pl[4] = {0.f, 0.f, 0.f, 0.f}, pr[4] = {0.f, 0.f, 0.f, 0.f};
#pragma unroll
        for (int nt = 0; nt < 4; nt++) {
            int n = n0 + wc + nt * 16 + l16;
#pragma unroll
            for (int r = 0; r < 4; r++) {
                float v = acc[mt][nt][r];
                if (m + r < N_NODES) feat16[(size_t)(m + r) * FDIM + n] = (_Float16)v;
                pl[r] += v * alv[nt];
                pr[r] += v * arv[nt];
            }
        }
#pragma unroll
        for (int r = 0; r < 4; r++) {
            float a = pl[r], b = pr[r];
            for (int off = 8; off; off >>= 1) {
                a += __shfl_down(a, off, 16);
                b += __shfl_down(b, off, 16);
            }
            if (l16 == 0 && m + r < N_NODES) {
                el[(m + r) * 4 + h] = a;
                er[(m + r) * 4 + h] = b;
            }
        }
    }
}

// ------------------------------------------- fused softmax + aggregate
// Single pass: numerator AND denominator accumulated together (no max pass —
// logits are O(1), exp cannot overflow; softmax ratio is max-invariant).
// Half-wave = edge slot (8 slots/block), 32 lanes x 8 fp16 feats, unroll x2.
// mode 0: write h1 as bf16 hi/lo (layer-2 GEMM PRESPLIT input, lives in d_out)
// mode 1: final fp32 head-major write
__global__ __launch_bounds__(256) void agg_fused(const _Float16* __restrict__ feat16,
                                                 const float* __restrict__ el,
                                                 const float* __restrict__ er,
                                                 const float* __restrict__ bias,
                                                 const int* __restrict__ offs,
                                                 const int* __restrict__ csr_src,
                                                 float* __restrict__ out,
                                                 unsigned short* __restrict__ h1h,
                                                 unsigned short* __restrict__ h1l,
                                                 int mode) {
    __shared__ float red[4][FDIM];
    __shared__ float sred[4][32];
    const int n = blockIdx.x;
    const int t = threadIdx.x;
    const int wave = t >> 6;
    const int lane = t & 63;
    const int half = lane >> 5;
    const int l32 = lane & 31;
    const int f0 = l32 * 8;
    const int hh = l32 >> 3;          // head of this lane's features
    const int beg = offs[n];
    const int end = offs[n + 1];

    const float er_h = er[n * 4 + hh];

    float acc[8] = {0.f, 0.f, 0.f, 0.f, 0.f, 0.f, 0.f, 0.f};
    float ssum = 0.f;
    int i = beg + wave * 2 + half;
    for (; i + 8 < end; i += 16) {
        int s0 = csr_src[i];
        int s1 = csr_src[i + 8];
        float e0 = el[s0 * 4 + hh] + er_h;
        float e1 = el[s1 * 4 + hh] + er_h;
        half8v v0 = *(const half8v*)&feat16[(size_t)s0 * FDIM + f0];
        half8v v1 = *(const half8v*)&feat16[(size_t)s1 * FDIM + f0];
        e0 = (e0 > 0.f) ? e0 : 0.2f * e0;
        e1 = (e1 > 0.f) ? e1 : 0.2f * e1;
        float w0 = __expf(e0), w1 = __expf(e1);
        ssum += w0 + w1;
#pragma unroll
        for (int j = 0; j < 8; j++) acc[j] += w0 * (float)v0[j] + w1 * (float)v1[j];
    }
    if (i < end) {
        int s0 = csr_src[i];
        float e0 = el[s0 * 4 + hh] + er_h;
        half8v v0 = *(const half8v*)&feat16[(size_t)s0 * FDIM + f0];
        e0 = (e0 > 0.f) ? e0 : 0.2f * e0;
        float w0 = __expf(e0);
        ssum += w0;
#pragma unroll
        for (int j = 0; j < 8; j++) acc[j] += w0 * (float)v0[j];
    }

#pragma unroll
    for (int j = 0; j < 8; j++) acc[j] += __shfl_xor(acc[j], 32);
    ssum += __shfl_xor(ssum, 32);
    if (lane < 32) {
        float4 a0 = make_float4(acc[0], acc[1], acc[2], acc[3]);
        float4 a1 = make_float4(acc[4], acc[5], acc[6], acc[7]);
        *(float4*)&red[wave][f0] = a0;
        *(float4*)&red[wave][f0 + 4] = a1;
        sred[wave][l32] = ssum;
    }
    __syncthreads();

    const int f = t;
    const int fh = f >> 6;
    const int d = f & 63;
    float numer = red[0][f] + red[1][f] + red[2][f] + red[3][f];
    float S = sred[0][fh * 8] + sred[1][fh * 8] + sred[2][fh * 8] + sred[3][fh * 8];
    float r = numer / fmaxf(S, 1e-9f) + bias[f];
    r = (r > 0.f) ? r : expm1f(r);
    if (mode) {
        out[(size_t)fh * N_NODES * HID + (size_t)n * HID + d] = r;
    } else {
        unsigned short hb = f2bf(r);
        h1h[(size_t)n * FDIM + f] = hb;
        h1l[(size_t)n * FDIM + f] = f2bf(r - bf2f(hb));
    }
}

// ---------------------------------------------------------------- launch

extern "C" void kernel_launch(void* const* d_in, const int* in_sizes, int n_in,
                              void* d_out, int out_size, void* d_ws, size_t ws_size,
                              hipStream_t stream) {
    const float* x   = (const float*)d_in[0];
    const int*   src = (const int*)d_in[1];
    const int*   dst = (const int*)d_in[2];
    const float* W0  = (const float*)d_in[3];
    const float* al0 = (const float*)d_in[4];
    const float* ar0 = (const float*)d_in[5];
    const float* b0  = (const float*)d_in[6];
    const float* W1  = (const float*)d_in[7];
    const float* al1 = (const float*)d_in[8];
    const float* ar1 = (const float*)d_in[9];
    const float* b1  = (const float*)d_in[10];
    float* out = (float*)d_out;

    // h1 (layer-1 hidden) stored pre-split bf16 hi/lo inside d_out:
    // 2 x N*256 ushorts = 51.2 MB = exactly out_size*4 bytes. Dead by the
    // time the final agg_fused(mode=1) overwrites d_out.
    unsigned short* h1h = (unsigned short*)d_out;
    unsigned short* h1l = h1h + (size_t)N_NODES * FDIM;

    // workspace layout
    _Float16* feat16 = (_Float16*)d_ws;                          // N*256 fp16
    unsigned short* bt0h = (unsigned short*)(feat16 + (size_t)N_NODES * FDIM);
    unsigned short* bt0l = bt0h + FDIM * FDIM;
    unsigned short* bt1h = bt0l + FDIM * FDIM;
    unsigned short* bt1l = bt1h + FDIM * FDIM;
    float* el    = (float*)(bt1l + FDIM * FDIM);                 // N*4
    float* er    = el + N_NODES * HEADS;                         // N*4
    int* counts  = (int*)(er + N_NODES * HEADS);                 // N
    int* cursor  = counts + N_NODES;                             // N
    int* offs    = cursor + N_NODES;                             // N+1 (pad 50016)
    int* bsum    = offs + 50016;                                 // 64
    int* csr_src = bsum + 64;                                    // E

    // ---- W prep + CSR build
    hipMemsetAsync(counts, 0, 2 * N_NODES * sizeof(int), stream);  // counts + cursor
    wsplit_kernel<<<dim3(16, 2), 256, 0, stream>>>(W0, W1, bt0h, bt0l, bt1h, bt1l);
    hist_kernel<<<(N_EDGES + 255) / 256, 256, 0, stream>>>(dst, counts, N_EDGES);
    scan_local<<<SCAN_NB, 256, 0, stream>>>(counts, offs, bsum, N_NODES);
    scan_bsum<<<1, 64, 0, stream>>>(bsum, offs, SCAN_NB, N_NODES);
    scan_add<<<SCAN_NB, 256, 0, stream>>>(offs, bsum, N_NODES);
    scatter_kernel<<<(N_EDGES + 255) / 256, 256, 0, stream>>>(src, dst, offs, cursor, csr_src, N_EDGES);

    dim3 ggrid((N_NODES + 127) / 128, FDIM / 128);

    // ---- layer 1 (h1 written pre-split into d_out)
    mfma_gemm<false><<<ggrid, 256, 0, stream>>>(x, nullptr, nullptr, bt0h, bt0l,
                                                al0, ar0, feat16, el, er);
    agg_fused<<<N_NODES, 256, 0, stream>>>(feat16, el, er, b0, offs, csr_src,
                                           out, h1h, h1l, 0);

    // ---- layer 2 (PRESPLIT A from d_out; final head-major write to d_out)
    mfma_gemm<true><<<ggrid, 256, 0, stream>>>(nullptr, h1h, h1l, bt1h, bt1l,
                                               al1, ar1, feat16, el, er);
    agg_fused<<<N_NODES, 256, 0, stream>>>(feat16, el, er, b1, offs, csr_src,
                                           out, h1h, h1l, 1);
}

// Round 6
// 385.878 us; speedup vs baseline: 2.7149x; 1.0948x over previous
//
#include <hip/hip_runtime.h>
#include <math.h>

#define N_NODES 50000
#define N_EDGES 800000
#define HEADS 4
#define HID 64
#define FDIM 256      // HEADS*HID == F_IN == 256 for both layers
#define LDA 40        // padded LDS k-stride (halves): 80B row stride
#define SCAN_CHUNK 1024
#define SCAN_NB ((N_NODES + SCAN_CHUNK - 1) / SCAN_CHUNK)   // 49

typedef __attribute__((ext_vector_type(8))) _Float16 half8;
typedef __attribute__((ext_vector_type(4))) _Float16 half4;
typedef __attribute__((ext_vector_type(4))) float f32x4;

// ---------------------------------------------------------------- CSR build

__global__ __launch_bounds__(256) void hist_kernel(const int* __restrict__ dst,
                                                   int* __restrict__ counts, int E) {
    int i = blockIdx.x * blockDim.x + threadIdx.x;
    if (i < E) atomicAdd(&counts[dst[i]], 1);
}

__global__ __launch_bounds__(256) void scan_local(const int* __restrict__ counts,
                                                  int* __restrict__ offs,
                                                  int* __restrict__ bsum, int n) {
    __shared__ int part[256];
    const int b = blockIdx.x, t = threadIdx.x;
    const int base = b * SCAN_CHUNK + t * 4;
    int v[4];
#pragma unroll
    for (int j = 0; j < 4; j++) {
        int idx = base + j;
        v[j] = (idx < n) ? counts[idx] : 0;
    }
    int s0 = v[0], s1 = s0 + v[1], s2 = s1 + v[2], s3 = s2 + v[3];
    part[t] = s3;
    __syncthreads();
    for (int off = 1; off < 256; off <<= 1) {
        int x = (t >= off) ? part[t - off] : 0;
        __syncthreads();
        part[t] += x;
        __syncthreads();
    }
    int prefix = (t > 0) ? part[t - 1] : 0;
    int e[4] = {prefix, prefix + s0, prefix + s1, prefix + s2};
#pragma unroll
    for (int j = 0; j < 4; j++) {
        int idx = base + j;
        if (idx < n) offs[idx] = e[j];
    }
    if (t == 255) bsum[b] = part[255];
}

__global__ __launch_bounds__(64) void scan_bsum(int* __restrict__ bsum,
                                                int* __restrict__ offs, int nb, int n) {
    int lane = threadIdx.x;
    int own = (lane < nb) ? bsum[lane] : 0;
    int v = own;
    for (int off = 1; off < 64; off <<= 1) {
        int x = __shfl_up(v, off);
        if (lane >= off) v += x;
    }
    if (lane < nb) bsum[lane] = v - own;   // exclusive prefix
    if (lane == nb - 1) offs[n] = v;       // grand total
}

__global__ __launch_bounds__(256) void scan_add(int* __restrict__ offs,
                                                const int* __restrict__ bsum, int n) {
    const int b = blockIdx.x;
    const int p = bsum[b];
    const int base = b * SCAN_CHUNK + threadIdx.x * 4;
#pragma unroll
    for (int j = 0; j < 4; j++) {
        int idx = base + j;
        if (idx < n) offs[idx] += p;
    }
}

__global__ __launch_bounds__(256) void scatter_kernel(const int* __restrict__ src,
                                                      const int* __restrict__ dst,
                                                      const int* __restrict__ offs,
                                                      int* __restrict__ cursor,
                                                      int* __restrict__ csr_src, int E) {
    int i = blockIdx.x * blockDim.x + threadIdx.x;
    if (i < E) {
        int d = dst[i];
        int p = offs[d] + atomicAdd(&cursor[d], 1);
        csr_src[p] = src[i];
    }
}

// -------------------------------------------- prep: W transpose-cast, x cast

__global__ __launch_bounds__(256) void wcast_kernel(const float* __restrict__ W0,
                                                    const float* __restrict__ W1,
                                                    _Float16* __restrict__ wt0,
                                                    _Float16* __restrict__ wt1) {
    const float* W = blockIdx.y ? W1 : W0;
    _Float16* wt = blockIdx.y ? wt1 : wt0;
    int n = blockIdx.x * 16 + (threadIdx.x >> 4);
    int k0 = (threadIdx.x & 15) * 16;
    for (int j = 0; j < 16; j++)
        wt[n * FDIM + k0 + j] = (_Float16)W[(k0 + j) * FDIM + n];
}

__global__ __launch_bounds__(256) void cast_x_kernel(const float* __restrict__ x,
                                                     _Float16* __restrict__ x16) {
    size_t i = ((size_t)blockIdx.x * 256 + threadIdx.x) * 4;
    float4 v = *(const float4*)&x[i];
    half4 h = {(_Float16)v.x, (_Float16)v.y, (_Float16)v.z, (_Float16)v.w};
    *(half4*)&x16[i] = h;
}

// -------------------------------------------- fp16 MFMA GEMM + fused el/er
// C = A16 @ W (W pre-cast/transposed: Bt[n][k]). feat16 written fp16;
// el/er computed in the epilogue from fp32 accumulators (wave's 64-col
// quadrant == one head; width-16 shuffle completes the reduction).
__global__ __launch_bounds__(256) void mfma_gemm(const _Float16* __restrict__ A16,
                                                 const _Float16* __restrict__ Bt,
                                                 const float* __restrict__ al,
                                                 const float* __restrict__ ar,
                                                 _Float16* __restrict__ feat16,
                                                 float* __restrict__ el,
                                                 float* __restrict__ er) {
    __shared__ _Float16 ash[128][LDA];
    __shared__ _Float16 bsh[128][LDA];

    const int t = threadIdx.x;
    const int m0 = blockIdx.x * 128;
    const int n0 = blockIdx.y * 128;
    const int wave = t >> 6, lane = t & 63;
    const int quad = lane >> 4, l16 = lane & 15;
    const int wr = (wave >> 1) * 64;
    const int wc = (wave & 1) * 64;

    const f32x4 zero = {0.f, 0.f, 0.f, 0.f};
    f32x4 acc[4][4];
#pragma unroll
    for (int i = 0; i < 4; i++)
#pragma unroll
        for (int j = 0; j < 4; j++) acc[i][j] = zero;

    for (int kk = 0; kk < FDIM; kk += 32) {
        // stage A and B tiles: 128 rows x 32 halves each; thread does 2 x 16B per array
#pragma unroll
        for (int ii = 0; ii < 2; ii++) {
            int idx = t + ii * 256;          // 0..511
            int row = idx >> 2;
            int kb = (idx & 3) * 8;
            int gr = m0 + row; if (gr >= N_NODES) gr = N_NODES - 1;
            *(half8*)&ash[row][kb] = *(const half8*)&A16[(size_t)gr * FDIM + kk + kb];
            *(half8*)&bsh[row][kb] = *(const half8*)&Bt[(size_t)(n0 + row) * FDIM + kk + kb];
        }
        __syncthreads();

        half8 af[4], bf[4];
#pragma unroll
        for (int i = 0; i < 4; i++) {
            af[i] = *(half8*)&ash[wr + i * 16 + l16][quad * 8];
            bf[i] = *(half8*)&bsh[wc + i * 16 + l16][quad * 8];
        }
#pragma unroll
        for (int mt = 0; mt < 4; mt++)
#pragma unroll
            for (int nt = 0; nt < 4; nt++)
                acc[mt][nt] = __builtin_amdgcn_mfma_f32_16x16x32_f16(af[mt], bf[nt], acc[mt][nt], 0, 0, 0);
        __syncthreads();
    }

    // ---- epilogue: feat16 store + fused el/er (this wave's head = h)
    const int h = (n0 + wc) >> 6;
    float alv[4], arv[4];
#pragma unroll
    for (int nt = 0; nt < 4; nt++) {
        alv[nt] = al[n0 + wc + nt * 16 + l16];
        arv[nt] = ar[n0 + wc + nt * 16 + l16];
    }
#pragma unroll
    for (int mt = 0; mt < 4; mt++) {
        int m = m0 + wr + mt * 16 + quad * 4;
        float pl[4] = {0.f, 0.f, 0.f, 0.f}, pr[4] = {0.f, 0.f, 0.f, 0.f};
#pragma unroll
        for (int nt = 0; nt < 4; nt++) {
            int n = n0 + wc + nt * 16 + l16;
#pragma unroll
            for (int r = 0; r < 4; r++) {
                float v = acc[mt][nt][r];
                if (m + r < N_NODES) feat16[(size_t)(m + r) * FDIM + n] = (_Float16)v;
                pl[r] += v * alv[nt];
                pr[r] += v * arv[nt];
            }
        }
#pragma unroll
        for (int r = 0; r < 4; r++) {
            float a = pl[r], b = pr[r];
            for (int off = 8; off; off >>= 1) {
                a += __shfl_down(a, off, 16);
                b += __shfl_down(b, off, 16);
            }
            if (l16 == 0 && m + r < N_NODES) {
                el[(m + r) * 4 + h] = a;
                er[(m + r) * 4 + h] = b;
            }
        }
    }
}

// ------------------------------------------- fused softmax + aggregate
// Wave per node, NO LDS / NO barriers. Lane owns features f=lane*4..+3
// (head = lane>>4); every lane walks ALL edges, so the per-head softmax
// denominator is complete in-register (identical across the head's 16 lanes).
// Single-pass (no max subtraction — logits are O(1), ratio is max-invariant).
// mode 0: write h1 as fp16 (layer-2 GEMM input, lives in d_out)
// mode 1: final fp32 head-major write
__global__ __launch_bounds__(256) void agg_fused(const _Float16* __restrict__ feat16,
                                                 const float* __restrict__ el,
                                                 const float* __restrict__ er,
                                                 const float* __restrict__ bias,
                                                 const int* __restrict__ offs,
                                                 const int* __restrict__ csr_src,
                                                 float* __restrict__ out,
                                                 _Float16* __restrict__ h1,
                                                 int mode) {
    const int wave = threadIdx.x >> 6;
    const int lane = threadIdx.x & 63;
    const int n = blockIdx.x * 4 + wave;
    const int head = lane >> 4;
    const int f = lane * 4;           // == head*64 + (lane&15)*4
    const int beg = offs[n];
    const int end = offs[n + 1];
    const float er_h = er[n * 4 + head];

    float4 acc0 = make_float4(0.f, 0.f, 0.f, 0.f);
    float4 acc1 = make_float4(0.f, 0.f, 0.f, 0.f);
    float ss0 = 0.f, ss1 = 0.f;

    int i = beg;
    for (; i + 3 < end; i += 4) {
        int s0 = csr_src[i], s1 = csr_src[i + 1];
        int s2 = csr_src[i + 2], s3 = csr_src[i + 3];
        float e0 = el[s0 * 4 + head] + er_h;
        float e1 = el[s1 * 4 + head] + er_h;
        float e2 = el[s2 * 4 + head] + er_h;
        float e3 = el[s3 * 4 + head] + er_h;
        half4 v0 = *(const half4*)&feat16[(size_t)s0 * FDIM + f];
        half4 v1 = *(const half4*)&feat16[(size_t)s1 * FDIM + f];
        half4 v2 = *(const half4*)&feat16[(size_t)s2 * FDIM + f];
        half4 v3 = *(const half4*)&feat16[(size_t)s3 * FDIM + f];
        e0 = (e0 > 0.f) ? e0 : 0.2f * e0;
        e1 = (e1 > 0.f) ? e1 : 0.2f * e1;
        e2 = (e2 > 0.f) ? e2 : 0.2f * e2;
        e3 = (e3 > 0.f) ? e3 : 0.2f * e3;
        float w0 = __expf(e0), w1 = __expf(e1), w2 = __expf(e2), w3 = __expf(e3);
        ss0 += w0 + w2;
        ss1 += w1 + w3;
        acc0.x += w0 * (float)v0[0] + w2 * (float)v2[0];
        acc0.y += w0 * (float)v0[1] + w2 * (float)v2[1];
        acc0.z += w0 * (float)v0[2] + w2 * (float)v2[2];
        acc0.w += w0 * (float)v0[3] + w2 * (float)v2[3];
        acc1.x += w1 * (float)v1[0] + w3 * (float)v3[0];
        acc1.y += w1 * (float)v1[1] + w3 * (float)v3[1];
        acc1.z += w1 * (float)v1[2] + w3 * (float)v3[2];
        acc1.w += w1 * (float)v1[3] + w3 * (float)v3[3];
    }
    for (; i < end; i++) {
        int s0 = csr_src[i];
        float e0 = el[s0 * 4 + head] + er_h;
        half4 v0 = *(const half4*)&feat16[(size_t)s0 * FDIM + f];
        e0 = (e0 > 0.f) ? e0 : 0.2f * e0;
        float w0 = __expf(e0);
        ss0 += w0;
        acc0.x += w0 * (float)v0[0];
        acc0.y += w0 * (float)v0[1];
        acc0.z += w0 * (float)v0[2];
        acc0.w += w0 * (float)v0[3];
    }

    float S = fmaxf(ss0 + ss1, 1e-9f);
    float inv = 1.f / S;
    float4 bv = *(const float4*)&bias[f];
    float r0 = (acc0.x + acc1.x) * inv + bv.x;
    float r1 = (acc0.y + acc1.y) * inv + bv.y;
    float r2 = (acc0.z + acc1.z) * inv + bv.z;
    float r3 = (acc0.w + acc1.w) * inv + bv.w;
    r0 = (r0 > 0.f) ? r0 : expm1f(r0);
    r1 = (r1 > 0.f) ? r1 : expm1f(r1);
    r2 = (r2 > 0.f) ? r2 : expm1f(r2);
    r3 = (r3 > 0.f) ? r3 : expm1f(r3);

    if (mode) {
        const int d = (lane & 15) * 4;
        float4 rv = make_float4(r0, r1, r2, r3);
        *(float4*)&out[(size_t)head * N_NODES * HID + (size_t)n * HID + d] = rv;
    } else {
        half4 hv = {(_Float16)r0, (_Float16)r1, (_Float16)r2, (_Float16)r3};
        *(half4*)&h1[(size_t)n * FDIM + f] = hv;
    }
}

// ---------------------------------------------------------------- launch

extern "C" void kernel_launch(void* const* d_in, const int* in_sizes, int n_in,
                              void* d_out, int out_size, void* d_ws, size_t ws_size,
                              hipStream_t stream) {
    const float* x   = (const float*)d_in[0];
    const int*   src = (const int*)d_in[1];
    const int*   dst = (const int*)d_in[2];
    const float* W0  = (const float*)d_in[3];
    const float* al0 = (const float*)d_in[4];
    const float* ar0 = (const float*)d_in[5];
    const float* b0  = (const float*)d_in[6];
    const float* W1  = (const float*)d_in[7];
    const float* al1 = (const float*)d_in[8];
    const float* ar1 = (const float*)d_in[9];
    const float* b1  = (const float*)d_in[10];
    float* out = (float*)d_out;

    // x16 (pre-cast input) and later h1 (layer-1 hidden, fp16) both live in
    // the first 25.6 MB of d_out. Timeline: cast_x writes x16 -> gemm-1 reads
    // x16 -> agg(mode0) overwrites with h1 -> gemm-2 reads h1 -> agg(mode1)
    // overwrites all of d_out with the final output. All sequential on stream.
    _Float16* x16h1 = (_Float16*)d_out;

    // workspace layout
    _Float16* feat16 = (_Float16*)d_ws;                          // N*256 fp16
    _Float16* wt0 = feat16 + (size_t)N_NODES * FDIM;             // 256*256
    _Float16* wt1 = wt0 + FDIM * FDIM;                           // 256*256
    float* el    = (float*)(wt1 + FDIM * FDIM);                  // N*4
    float* er    = el + N_NODES * HEADS;                         // N*4
    int* counts  = (int*)(er + N_NODES * HEADS);                 // N
    int* cursor  = counts + N_NODES;                             // N
    int* offs    = cursor + N_NODES;                             // N+1 (pad 50016)
    int* bsum    = offs + 50016;                                 // 64
    int* csr_src = bsum + 64;                                    // E

    // ---- prep + CSR build
    hipMemsetAsync(counts, 0, 2 * N_NODES * sizeof(int), stream);  // counts + cursor
    wcast_kernel<<<dim3(16, 2), 256, 0, stream>>>(W0, W1, wt0, wt1);
    cast_x_kernel<<<N_NODES * FDIM / 1024, 256, 0, stream>>>(x, x16h1);
    hist_kernel<<<(N_EDGES + 255) / 256, 256, 0, stream>>>(dst, counts, N_EDGES);
    scan_local<<<SCAN_NB, 256, 0, stream>>>(counts, offs, bsum, N_NODES);
    scan_bsum<<<1, 64, 0, stream>>>(bsum, offs, SCAN_NB, N_NODES);
    scan_add<<<SCAN_NB, 256, 0, stream>>>(offs, bsum, N_NODES);
    scatter_kernel<<<(N_EDGES + 255) / 256, 256, 0, stream>>>(src, dst, offs, cursor, csr_src, N_EDGES);

    dim3 ggrid((N_NODES + 127) / 128, FDIM / 128);

    // ---- layer 1 (h1 fp16 written into d_out)
    mfma_gemm<<<ggrid, 256, 0, stream>>>(x16h1, wt0, al0, ar0, feat16, el, er);
    agg_fused<<<N_NODES / 4, 256, 0, stream>>>(feat16, el, er, b0, offs, csr_src,
                                               out, x16h1, 0);

    // ---- layer 2 (reads h1 fp16; final head-major fp32 write to d_out)
    mfma_gemm<<<ggrid, 256, 0, stream>>>(x16h1, wt1, al1, ar1, feat16, el, er);
    agg_fused<<<N_NODES / 4, 256, 0, stream>>>(feat16, el, er, b1, offs, csr_src,
                                               out, x16h1, 1);
}